// Round 9
// baseline (227.368 us; speedup 1.0000x reference)
//
#include <hip/hip_runtime.h>
#include <math.h>

#define B_ 32
#define C_ 3
#define H_ 256
#define W_ 832
#define HW_ (H_*W_)
#define NQ (W_/4)               // 208 quads (float4 columns) per row
#define K_ 100
#define RPB 16                  // rows per block
#define PARTS (H_/RPB)          // 16 parts per channel
#define BLK 256
#define CAP 2048                // per-part LDS candidate cap (expected ~1480)
#define NB 2048                 // merge radix bins (11-bit digits)
#define NB8 256                 // part fallback radix bins (8-bit digits)
#define TIE_CAP 128
#define SEL_PASSES 6
#define SEL_PASSES8 8
#define QPW 62                  // emitting quads per wave (overlapped mapping)
#define SA 128                  // tier-A slots/part (expected ~7 keys)
#define SB 512                  // tier-B slots/part (expected ~215 keys)
#define T_A 0.9995f             // tier-A threshold: ~320 keys/batch >= T_A
#define T_B 0.982f              // tier-B floor (insurance tier)
#define PPB (C_*PARTS)          // 48 parts per batch
#define SLAB (SA+SB)

typedef unsigned long long ull;

// Descending bitonic sort of N (power of two) 64-bit keys in LDS (small N only).
template<int N>
__device__ inline void bitonic_sort_desc(ull* s) {
    for (int k = 2; k <= N; k <<= 1) {
        for (int j = k >> 1; j > 0; j >>= 1) {
            __syncthreads();
            for (int i = threadIdx.x; i < N; i += BLK) {
                int ixj = i ^ j;
                if (ixj > i) {
                    ull a = s[i], b = s[ixj];
                    bool up = ((i & k) == 0);
                    if (up ? (a < b) : (a > b)) { s[i] = b; s[ixj] = a; }
                }
            }
        }
    }
    __syncthreads();
}

// find threshold digit in hist[NB] (2048 bins, 8/thread). 2 barriers.
__device__ inline void find_digit(const unsigned* __restrict__ hist,
                                  unsigned* __restrict__ wtot,
                                  const int kneed,
                                  int* __restrict__ d_s,
                                  int* __restrict__ krem_s,
                                  int* __restrict__ m_s) {
    const int tid = threadIdx.x;
    const int lane = tid & 63;
    const int wid = tid >> 6;
    unsigned l[8];
    unsigned Ls = 0;
    #pragma unroll
    for (int j = 0; j < 8; ++j) { l[j] = hist[tid * 8 + j]; Ls += l[j]; }
    unsigned x = Ls;
    #pragma unroll
    for (int off = 1; off < 64; off <<= 1) {
        unsigned y = __shfl_down(x, off);
        if (lane + off < 64) x += y;
    }
    if (lane == 0) wtot[wid] = x;   // wave totals
    __syncthreads();
    unsigned tail = 0;
    #pragma unroll
    for (int w = 0; w < 4; ++w) if (w > wid) tail += wtot[w];
    unsigned s = x - Ls + tail;     // count of keys strictly above this range
    #pragma unroll
    for (int j = 7; j >= 0; --j) {
        const unsigned Sj = s + l[j];
        if (Sj >= (unsigned)kneed && s < (unsigned)kneed) {  // unique thread
            *d_s = tid * 8 + j;
            *krem_s = kneed - (int)s;
            *m_s = (int)l[j];
        }
        s = Sj;
    }
    __syncthreads();
}

// 256-bin variant (1 bin/thread) — part-kernel fallback only.
__device__ inline void find_digit8(const unsigned* __restrict__ hist8,
                                   unsigned* __restrict__ wtot,
                                   const int kneed,
                                   int* __restrict__ d_s,
                                   int* __restrict__ krem_s,
                                   int* __restrict__ m_s) {
    const int tid = threadIdx.x;
    const int lane = tid & 63;
    const int wid = tid >> 6;
    const unsigned l = hist8[tid];
    unsigned x = l;
    #pragma unroll
    for (int off = 1; off < 64; off <<= 1) {
        unsigned y = __shfl_down(x, off);
        if (lane + off < 64) x += y;
    }
    if (lane == 0) wtot[wid] = x;
    __syncthreads();
    unsigned tail = 0;
    #pragma unroll
    for (int w = 0; w < 4; ++w) if (w > wid) tail += wtot[w];
    const unsigned s = x - l + tail;
    if (s + l >= (unsigned)kneed && s < (unsigned)kneed) {
        *d_s = tid; *krem_s = kneed - (int)s; *m_s = (int)l;
    }
    __syncthreads();
}

// ---------------------------------------------------------------------------
// Exact top-K_ select, 2048-bin MSB-first radix w/ early-exit tie rank.
// Used by merge (LDS source). sh: int[5] {ocnt, tcnt, d, krem, m}.
// ---------------------------------------------------------------------------
__device__ inline void select_topk(const ull* __restrict__ buf, const int cnt,
                                   ull* __restrict__ dst,
                                   unsigned* __restrict__ hist,
                                   ull* __restrict__ tie,
                                   unsigned* __restrict__ wtot,
                                   int* __restrict__ sh) {
    const int tid = threadIdx.x;
    const int lane = tid & 63;
    if (tid == 0) sh[0] = 0;                 // ocnt
    int kneed = K_;
    int pshift = 0;                          // valid for pass > 0
    ull prefix = 0;
    for (int pass = 0; pass < SEL_PASSES; ++pass) {
        const int rs = 53 - 11 * pass;
        const int shift = (rs > 0) ? rs : 0;
        #pragma unroll
        for (int j = 0; j < NB / BLK; ++j) hist[tid + j * BLK] = 0u;
        if (tid == 0) sh[1] = 0;             // tcnt
        __syncthreads();
        if (pass == 0) {
            for (int i = tid; i < cnt; i += BLK) {
                const unsigned dg = (unsigned)(buf[i] >> shift) & 2047u;
                ull unclaimed = __ballot(1);
                while (unclaimed) {
                    const int leader = __ffsll((long long)unclaimed) - 1;
                    const unsigned ldg = __shfl(dg, leader);
                    const ull same = __ballot(dg == ldg);
                    if (lane == leader)
                        atomicAdd(&hist[ldg], (unsigned)__popcll(same));
                    unclaimed &= ~same;
                }
            }
        } else {
            for (int i = tid; i < cnt; i += BLK) {
                const ull key = buf[i];
                if ((key >> pshift) != prefix) continue;
                atomicAdd(&hist[(unsigned)(key >> shift) & 2047u], 1u);
            }
        }
        __syncthreads();
        find_digit(hist, wtot, kneed, &sh[2], &sh[3], &sh[4]);
        const int d = sh[2], krem = sh[3], m = sh[4];
        const bool last = (m <= TIE_CAP) || (pass == SEL_PASSES - 1);
        for (int i = tid; i < cnt; i += BLK) {
            const ull key = buf[i];
            if (pass > 0 && (key >> pshift) != prefix) continue;
            const int dg = (int)((unsigned)(key >> shift) & 2047u);
            if (dg > d) {
                dst[atomicAdd(&sh[0], 1)] = key;
            } else if (last && dg == d) {
                const int p = atomicAdd(&sh[1], 1);
                if (p < TIE_CAP) tie[p] = key;
            }
        }
        __syncthreads();
        if (last) {
            const int n1 = K_ - krem;
            if (sh[1] <= TIE_CAP) {
                const int mm = sh[1];
                for (int i = tid; i < mm; i += BLK) {
                    const ull key = tie[i];
                    int r = 0;
                    for (int j = 0; j < mm; ++j) r += (tie[j] > key) ? 1 : 0;
                    if (r < krem) dst[n1 + r] = key;
                }
            } else {
                for (int i = tid; i < krem; i += BLK) dst[n1 + i] = tie[0];
            }
            __syncthreads();
            return;
        }
        prefix = (prefix << 11) | (ull)(unsigned)d;
        pshift = shift;
        kneed = krem;
    }
}

// 256-bin variant for the part-kernel fallback (never taken in practice;
// only its 1 KB LDS footprint matters — it buys 8 blocks/CU occupancy).
__device__ inline void select_topk8(const ull* __restrict__ buf, const int cnt,
                                    ull* __restrict__ dst,
                                    unsigned* __restrict__ hist8,
                                    ull* __restrict__ tie,
                                    unsigned* __restrict__ wtot,
                                    int* __restrict__ sh) {
    const int tid = threadIdx.x;
    const int lane = tid & 63;
    if (tid == 0) sh[0] = 0;                 // ocnt
    int kneed = K_;
    int pshift = 0;
    ull prefix = 0;
    for (int pass = 0; pass < SEL_PASSES8; ++pass) {
        const int shift = 56 - 8 * pass;
        hist8[tid] = 0u;
        if (tid == 0) sh[1] = 0;             // tcnt
        __syncthreads();
        if (pass == 0) {
            for (int i = tid; i < cnt; i += BLK) {
                const unsigned dg = (unsigned)(buf[i] >> shift) & 255u;
                ull unclaimed = __ballot(1);
                while (unclaimed) {
                    const int leader = __ffsll((long long)unclaimed) - 1;
                    const unsigned ldg = __shfl(dg, leader);
                    const ull same = __ballot(dg == ldg);
                    if (lane == leader)
                        atomicAdd(&hist8[ldg], (unsigned)__popcll(same));
                    unclaimed &= ~same;
                }
            }
        } else {
            for (int i = tid; i < cnt; i += BLK) {
                const ull key = buf[i];
                if ((key >> pshift) != prefix) continue;
                atomicAdd(&hist8[(unsigned)(key >> shift) & 255u], 1u);
            }
        }
        __syncthreads();
        find_digit8(hist8, wtot, kneed, &sh[2], &sh[3], &sh[4]);
        const int d = sh[2], krem = sh[3], m = sh[4];
        const bool last = (m <= TIE_CAP) || (pass == SEL_PASSES8 - 1);
        for (int i = tid; i < cnt; i += BLK) {
            const ull key = buf[i];
            if (pass > 0 && (key >> pshift) != prefix) continue;
            const int dg = (int)((unsigned)(key >> shift) & 255u);
            if (dg > d) {
                dst[atomicAdd(&sh[0], 1)] = key;
            } else if (last && dg == d) {
                const int p = atomicAdd(&sh[1], 1);
                if (p < TIE_CAP) tie[p] = key;
            }
        }
        __syncthreads();
        if (last) {
            const int n1 = K_ - krem;
            if (sh[1] <= TIE_CAP) {
                const int mm = sh[1];
                for (int i = tid; i < mm; i += BLK) {
                    const ull key = tie[i];
                    int r = 0;
                    for (int j = 0; j < mm; ++j) r += (tie[j] > key) ? 1 : 0;
                    if (r < krem) dst[n1 + r] = key;
                }
            } else {
                for (int i = tid; i < krem; i += BLK) dst[n1 + i] = tie[0];
            }
            __syncthreads();
            return;
        }
        prefix = (prefix << 8) | (ull)(unsigned)d;
        pshift = shift;
        kneed = krem;
    }
}

// 2048-bin select over a global array (merge slow path; never in practice).
__device__ inline void select_topk_g(const ull* __restrict__ A, const int cnt,
                                     ull* __restrict__ dst,
                                     unsigned* __restrict__ hist,
                                     ull* __restrict__ tie,
                                     unsigned* __restrict__ wtot,
                                     int* __restrict__ sh) {
    const int tid = threadIdx.x;
    const int lane = tid & 63;
    if (tid == 0) sh[0] = 0;
    int kneed = K_;
    int pshift = 0;
    ull prefix = 0;
    for (int pass = 0; pass < SEL_PASSES; ++pass) {
        const int rs = 53 - 11 * pass;
        const int shift = (rs > 0) ? rs : 0;
        #pragma unroll
        for (int j = 0; j < NB / BLK; ++j) hist[tid + j * BLK] = 0u;
        if (tid == 0) sh[1] = 0;
        __syncthreads();
        if (pass == 0) {
            for (int i = tid; i < cnt; i += BLK) {
                const unsigned dg = (unsigned)(A[i] >> shift) & 2047u;
                ull unclaimed = __ballot(1);
                while (unclaimed) {
                    const int leader = __ffsll((long long)unclaimed) - 1;
                    const unsigned ldg = __shfl(dg, leader);
                    const ull same = __ballot(dg == ldg);
                    if (lane == leader)
                        atomicAdd(&hist[ldg], (unsigned)__popcll(same));
                    unclaimed &= ~same;
                }
            }
        } else {
            for (int i = tid; i < cnt; i += BLK) {
                const ull key = A[i];
                if ((key >> pshift) != prefix) continue;
                atomicAdd(&hist[(unsigned)(key >> shift) & 2047u], 1u);
            }
        }
        __syncthreads();
        find_digit(hist, wtot, kneed, &sh[2], &sh[3], &sh[4]);
        const int d = sh[2], krem = sh[3], m = sh[4];
        const bool last = (m <= TIE_CAP) || (pass == SEL_PASSES - 1);
        for (int i = tid; i < cnt; i += BLK) {
            const ull key = A[i];
            if (pass > 0 && (key >> pshift) != prefix) continue;
            const int dg = (int)((unsigned)(key >> shift) & 2047u);
            if (dg > d) {
                dst[atomicAdd(&sh[0], 1)] = key;
            } else if (last && dg == d) {
                const int p = atomicAdd(&sh[1], 1);
                if (p < TIE_CAP) tie[p] = key;
            }
        }
        __syncthreads();
        if (last) {
            const int n1 = K_ - krem;
            if (sh[1] <= TIE_CAP) {
                const int mm = sh[1];
                for (int i = tid; i < mm; i += BLK) {
                    const ull key = tie[i];
                    int r = 0;
                    for (int j = 0; j < mm; ++j) r += (tie[j] > key) ? 1 : 0;
                    if (r < krem) dst[n1 + r] = key;
                }
            } else {
                for (int i = tid; i < krem; i += BLK) dst[n1 + i] = tie[0];
            }
            __syncthreads();
            return;
        }
        prefix = (prefix << 11) | (ull)(unsigned)d;
        pshift = shift;
        kneed = krem;
    }
}

// ---------------------------------------------------------------------------
// Kernel 1: separable 3x3 peak detect (row loop as R4) + two-tier epilogue
// (as R8), with two occupancy/latency changes:
//  - fallback select uses 256-bin radix -> hist LDS 8 KB -> 1 KB; block LDS
//    25.7 KB -> 18.5 KB -> 8 blocks/CU (32 waves/CU, HW cap) for the
//    latency-bound cold-HBM stream.
//  - tier counts (nA/nB) accumulated IN the row loop via ballots (one LDS
//    atomic per wave at the end) — the epilogue's count pass is deleted.
//    If scnt > CAP (keys dropped, +15-sigma; same exposure as all prior
//    rounds) the epilogue recounts over the retained keys, restoring R8
//    semantics exactly.
// ---------------------------------------------------------------------------
__global__ void __launch_bounds__(BLK) topk_part_kernel(
        const float* __restrict__ heat, ull* __restrict__ parts2,
        unsigned* __restrict__ cnts) {
    const int chan = blockIdx.x / PARTS;   // b*C + c
    const int c    = chan % C_;
    const int part = blockIdx.x % PARTS;
    const float* __restrict__ hp = heat + (size_t)chan * HW_;
    const int r0 = part * RPB;
    const int tid = threadIdx.x;
    const int lane = tid & 63;
    const int wid = tid >> 6;

    const int q = QPW * wid + lane - 1;          // quad this lane carries
    const bool ghost = (q < 0) || (q >= NQ);     // outside image -> -inf colmax
    const int qc = (q < 0) ? 0 : ((q >= NQ) ? NQ - 1 : q);
    const bool emitter = (lane >= 1) && (lane <= QPW) && !ghost;

    __shared__ ull sbuf[CAP];
    __shared__ unsigned hist8[NB8];
    __shared__ ull tie[TIE_CAP];
    __shared__ unsigned wtot[4];
    __shared__ int scnt, nA, nB, wpA, wpB;
    __shared__ int selsh[5];
    if (tid == 0) { scnt = 0; nA = 0; nB = 0; wpA = 0; wpB = 0; }

    float4 R[6];
    #pragma unroll
    for (int j = 0; j < 6; ++j) {
        int row = r0 - 1 + j;
        row = (row < 0) ? 0 : ((row > H_ - 1) ? H_ - 1 : row);
        R[j] = reinterpret_cast<const float4*>(hp + (size_t)row * W_)[qc];
    }
    __syncthreads();   // counters=0 visible before any append

    int waveA = 0, waveB = 0;   // per-wave tier tallies (lane 0 meaningful)

    #pragma unroll
    for (int r = 0; r < RPB; ++r) {
        const int y = r0 + r;
        const float4 ra = R[r % 6];
        const float4 rb = R[(r + 1) % 6];
        const float4 rc = R[(r + 2) % 6];
        if (r < RPB - 4) {
            const int yn = (y + 5 > H_ - 1) ? H_ - 1 : y + 5;
            R[r % 6] = reinterpret_cast<const float4*>(hp + (size_t)yn * W_)[qc];
        }

        float4 vm;
        vm.x = fmaxf(fmaxf(ra.x, rb.x), rc.x);
        vm.y = fmaxf(fmaxf(ra.y, rb.y), rc.y);
        vm.z = fmaxf(fmaxf(ra.z, rb.z), rc.z);
        vm.w = fmaxf(fmaxf(ra.w, rb.w), rc.w);
        if (ghost) { vm.x = vm.y = vm.z = vm.w = -INFINITY; }

        const float left  = __shfl_up(vm.w, 1);
        const float right = __shfl_down(vm.x, 1);

        const float vn[6] = {left, vm.x, vm.y, vm.z, vm.w, right};
        const float vv[4] = {rb.x, rb.y, rb.z, rb.w};
        ull m[4];
        bool pk[4];
        #pragma unroll
        for (int i = 0; i < 4; ++i) {
            pk[i] = emitter && (vv[i] >= vn[i]) && (vv[i] >= vn[i+1]) && (vv[i] >= vn[i+2]);
            m[i] = __ballot(pk[i]);
            // in-loop tier tallies (counts ALL peaks, incl. any CAP-dropped)
            waveA += (int)__popcll(__ballot(pk[i] && vv[i] >= T_A));
            waveB += (int)__popcll(__ballot(pk[i] && vv[i] >= T_B && vv[i] < T_A));
        }
        const int tot = (int)(__popcll(m[0]) + __popcll(m[1]) +
                              __popcll(m[2]) + __popcll(m[3]));
        if (tot) {           // wave-uniform
            int base = 0;
            if (lane == 0) base = atomicAdd(&scnt, tot);
            base = __shfl(base, 0);
            int off = 0;
            #pragma unroll
            for (int i = 0; i < 4; ++i) {
                if (pk[i]) {
                    const unsigned p = (unsigned)(y * W_ + q * 4 + i);
                    const unsigned tiek = ((unsigned)c << 18) | p;
                    const ull key = ((ull)__float_as_uint(vv[i]) << 32) | (ull)(~tiek);
                    const int rank = (int)__popcll(m[i] & ((1ULL << lane) - 1ULL));
                    const int pos = base + off + rank;
                    if (pos < CAP) sbuf[pos] = key;
                }
                off += (int)__popcll(m[i]);
            }
        }
    }
    if (lane == 0) {
        if (waveA) atomicAdd(&nA, waveA);
        if (waveB) atomicAdd(&nB, waveB);
    }
    __syncthreads();   // scnt, sbuf, nA, nB final

    int cc = (scnt < CAP) ? scnt : CAP;
    if (scnt > CAP) {
        // rare overflow: recount tiers over RETAINED keys (restores R8 exactly)
        if (tid == 0) { nA = 0; nB = 0; }
        __syncthreads();
        int wA = 0, wB = 0;
        for (int i0 = wid * 64; i0 < cc; i0 += BLK) {
            const int i = i0 + lane;
            float v = -1.f;
            if (i < cc) v = __uint_as_float((unsigned)(sbuf[i] >> 32));
            wA += (int)__popcll(__ballot(v >= T_A));
            wB += (int)__popcll(__ballot(v >= T_B && v < T_A));
        }
        if (lane == 0) {
            if (wA) atomicAdd(&nA, wA);
            if (wB) atomicAdd(&nB, wB);
        }
        __syncthreads();
    }
    const int nhA = nA, nhB = nB;
    const bool fb = (nhA > SA) || (nhB > SB) ||
                    ((nhA + nhB) < K_ && (nhA + nhB) < cc);

    ull* oA = parts2 + (size_t)blockIdx.x * SLAB;
    ull* oB = oA + SA;
    int cntA, gA, cntB;
    if (cc <= K_) {
        // few candidates: emit everything into A (complete, nothing dropped)
        for (int i = tid; i < cc; i += BLK) oA[i] = sbuf[i];
        for (int i = cc + tid; i < SA; i += BLK) oA[i] = 0ULL;
        for (int i = tid; i < SB; i += BLK) oB[i] = 0ULL;
        cntA = cc; gA = (nhA < cc) ? nhA : cc; cntB = 0;
    } else if (!fb) {
        // common path: compact A and B tiers (no select)
        for (int i0 = wid * 64; i0 < cc; i0 += BLK) {
            const int i = i0 + lane;
            ull key = 0ULL; float v = -1.f;
            if (i < cc) { key = sbuf[i]; v = __uint_as_float((unsigned)(key >> 32)); }
            const bool fa  = (v >= T_A);
            const bool fbb = (v >= T_B) && (v < T_A);
            const ull ma = __ballot(fa);
            const ull mb = __ballot(fbb);
            int ba = 0, bb = 0;
            if (lane == 0) {
                if (ma) ba = atomicAdd(&wpA, (int)__popcll(ma));
                if (mb) bb = atomicAdd(&wpB, (int)__popcll(mb));
            }
            ba = __shfl(ba, 0); bb = __shfl(bb, 0);
            if (fa)  oA[ba + (int)__popcll(ma & ((1ULL << lane) - 1ULL))] = key;
            if (fbb) oB[bb + (int)__popcll(mb & ((1ULL << lane) - 1ULL))] = key;
        }
        for (int i = nhA + tid; i < SA; i += BLK) oA[i] = 0ULL;
        for (int i = nhB + tid; i < SB; i += BLK) oB[i] = 0ULL;
        cntA = nhA; gA = nhA; cntB = nhB;
    } else {
        // airtight fallback: exact part top-100 into A (256-bin radix)
        select_topk8(sbuf, cc, oA, hist8, tie, wtot, selsh);
        for (int i = K_ + tid; i < SA; i += BLK) oA[i] = 0ULL;
        for (int i = tid; i < SB; i += BLK) oB[i] = 0ULL;
        cntA = K_; gA = (nhA < K_) ? nhA : K_; cntB = 0;
    }
    if (tid == 0)
        cnts[blockIdx.x] = (unsigned)cntA | ((unsigned)gA << 8) |
                           ((unsigned)cntB << 16);
}

// ---------------------------------------------------------------------------
// Kernel 2 (fused merge+geom): unchanged from R8. Fast path: gather ~320
// tier-A keys into LDS and select there (provably sufficient when Sum gA
// >= 100). Slow path: padded A||B slab scan. Then sort-128 + geometry.
// ---------------------------------------------------------------------------
__global__ void __launch_bounds__(BLK) merge_geom_kernel(
        const ull* __restrict__ parts2, const unsigned* __restrict__ cnts,
        const float* __restrict__ reg,
        const float* __restrict__ trans, const float* __restrict__ Km,
        const float* __restrict__ sz, const float* __restrict__ hcam,
        const float* __restrict__ dimen, float* __restrict__ out) {
    const int b = blockIdx.x;
    const int tid = threadIdx.x;
    __shared__ ull buf[CAP];
    __shared__ unsigned hist[NB];
    __shared__ ull sel[128];
    __shared__ ull tie[TIE_CAP];
    __shared__ unsigned wtot[4];
    __shared__ int selsh[5];
    __shared__ int cA[PPB], gAsh[PPB], offA[PPB + 1];
    __shared__ int gsum_s;

    const int p0 = b * PPB;
    if (tid < PPB) {
        const unsigned w = cnts[p0 + tid];
        cA[tid]  = (int)(w & 255u);
        gAsh[tid] = (int)((w >> 8) & 255u);
    }
    if (tid < 128) sel[tid] = 0ULL;
    __syncthreads();
    if (tid == 0) {
        int acc = 0, g = 0;
        for (int j = 0; j < PPB; ++j) { offA[j] = acc; acc += cA[j]; g += gAsh[j]; }
        offA[PPB] = acc; gsum_s = g;
    }
    __syncthreads();
    const int ntot = offA[PPB];
    const int gsum = gsum_s;

    if (gsum >= K_ && ntot <= CAP) {
        // flattened gather of counted A prefixes
        for (int t = tid; t < ntot; t += BLK) {
            int j = 0;
            while (offA[j + 1] <= t) ++j;
            buf[t] = parts2[(size_t)(p0 + j) * SLAB + (t - offA[j])];
        }
        __syncthreads();
        if (ntot <= K_) {
            for (int i = tid; i < ntot; i += BLK) sel[i] = buf[i];
            __syncthreads();
        } else {
            select_topk(buf, ntot, sel, hist, tie, wtot, selsh);
        }
    } else {
        // airtight slow path: scan the full zero-padded A||B slab
        select_topk_g(parts2 + (size_t)p0 * SLAB, PPB * SLAB,
                      sel, hist, tie, wtot, selsh);
    }

    bitonic_sort_desc<128>(sel);   // has leading __syncthreads

    // ---- geometry, one thread per detection ----
    for (int i = tid; i < K_; i += BLK) {
        const ull key = sel[i];
        const unsigned tiek = ~(unsigned)(key & 0xFFFFFFFFULL);
        const float score = __uint_as_float((unsigned)(key >> 32));
        const float clsf = (float)((tiek >> 18) & 3u);
        unsigned hw = tiek & 0x3FFFFu;
        if (hw >= HW_) hw = 0;   // pad entries: score==0, row zeroed below
        const float xs = (float)(hw % W_);
        const float ys = (float)(hw / W_);

        const float* rg = reg + (size_t)b * 4 * HW_;
        const float delta = rg[hw];
        const float off_u = rg[HW_ + hw];
        const float ori0  = rg[2 * HW_ + hw];
        const float ori1  = rg[3 * HW_ + hw];

        const float* T = trans + b * 9;
        const float t00=T[0], t01=T[1], t02=T[2], t10=T[3], t11=T[4], t12=T[5],
                    t20=T[6], t21=T[7], t22=T[8];
        const float det3 = t00*(t11*t22 - t12*t21) - t01*(t10*t22 - t12*t20)
                         + t02*(t10*t21 - t11*t20);
        const float idt = 1.0f / det3;
        const float i00 = (t11*t22 - t12*t21)*idt;
        const float i01 = (t02*t21 - t01*t22)*idt;
        const float i02 = (t01*t12 - t02*t11)*idt;

        const float pu = xs + off_u;
        const float img_x = i00*pu + i01*ys + i02;

        const float* Kb = Km + b * 9;
        const float k00=Kb[0],k01=Kb[1],k02=Kb[2],k10=Kb[3],k11=Kb[4],k12=Kb[5],
                    k20=Kb[6],k21=Kb[7],k22=Kb[8];
        const float fx = k00, fy = k11, cx = k02;
        const float h = hcam[b];
        float d0 = dimen[b*3+0], d1 = dimen[b*3+1], d2 = dimen[b*3+2];
        if (!isfinite(d0)) d0 = 3.88f;
        if (!isfinite(d1)) d1 = 1.63f;
        if (!isfinite(d2)) d2 = 1.53f;

        const float h_ref = h - d1 * 0.5f;
        const float fyh = fy * fabsf(h_ref);
        const float log_dv_ref = logf(fmaxf(fyh, 1e-7f) / 28.01f);
        const float log_dv = fminf(fmaxf(log_dv_ref + delta, -4.0f), 8.0f);
        const float depth = fminf(fmaxf(fyh * expf(-log_dv), 0.5f), 120.0f);
        const float px = (img_x - cx) * depth / fx;

        const float PI_F  = 3.14159265358979323846f;
        const float ray = atanf(px / (depth + 1e-7f));
        float alpha = atanf(ori0 / (ori1 + 1e-7f));
        alpha += (ori1 >= 0.0f) ? -1.5707963267948966f : 1.5707963267948966f;
        float roty = alpha + ray;
        if (roty >  PI_F) roty -= 6.283185307179586f;
        if (roty < -PI_F) roty += 6.283185307179586f;

        const float cosr = cosf(roty), sinr = sinf(roty);
        const float cx8[8] = {-0.5f, 0.5f, 0.5f, 0.5f, 0.5f,-0.5f,-0.5f,-0.5f};
        const float cy8[8] = {-1.0f,-1.0f, 0.0f, 0.0f,-1.0f,-1.0f, 0.0f, 0.0f};
        const float cz8[8] = {-0.5f,-0.5f,-0.5f, 0.5f, 0.5f, 0.5f, 0.5f,-0.5f};
        float umin = 1e30f, umax = -1e30f, vmin = 1e30f, vmax = -1e30f;
        #pragma unroll
        for (int j = 0; j < 8; ++j) {
            const float xc = d0 * cx8[j];
            const float yc = d1 * cy8[j];
            const float zc = d2 * cz8[j];
            const float X = cosr*xc + sinr*zc + px;
            const float Y = yc + h;
            const float Z = -sinr*xc + cosr*zc + depth;
            const float w = k20*X + k21*Y + k22*Z;
            const float u = (k00*X + k01*Y + k02*Z) / w;
            const float v = (k10*X + k11*Y + k12*Z) / w;
            umin = fminf(umin, u); umax = fmaxf(umax, u);
            vmin = fminf(vmin, v); vmax = fmaxf(vmax, v);
        }
        const float img_w = sz[0], img_h = sz[1];
        const float xmin = fminf(fmaxf(umin, 0.0f), img_w);
        const float xmax = fminf(fmaxf(umax, 0.0f), img_w);
        const float ymin = fminf(fmaxf(vmin, 0.0f), img_h);
        const float ymax = fminf(fmaxf(vmax, 0.0f), img_h);

        const float keep = (score > 0.25f) ? 1.0f : 0.0f;
        float* o = out + (size_t)(b * K_ + i) * 14;
        o[0]  = clsf  * keep;
        o[1]  = alpha * keep;
        o[2]  = xmin  * keep;
        o[3]  = ymin  * keep;
        o[4]  = xmax  * keep;
        o[5]  = ymax  * keep;
        o[6]  = d1    * keep;   // pred_dims = roll(dims,-1)
        o[7]  = d2    * keep;
        o[8]  = d0    * keep;
        o[9]  = px    * keep;
        o[10] = h     * keep;
        o[11] = depth * keep;
        o[12] = roty  * keep;
        o[13] = score * keep;
    }
}

extern "C" void kernel_launch(void* const* d_in, const int* in_sizes, int n_in,
                              void* d_out, int out_size, void* d_ws, size_t ws_size,
                              hipStream_t stream) {
    const float* heat  = (const float*)d_in[0];  // (32,3,256,832)
    const float* reg   = (const float*)d_in[1];  // (32,4,256,832)
    const float* trans = (const float*)d_in[2];  // (32,3,3)
    const float* Kmat  = (const float*)d_in[3];  // (32,3,3)
    const float* sz    = (const float*)d_in[4];  // (32,2)
    const float* hcam  = (const float*)d_in[5];  // (32,)
    const float* dimen = (const float*)d_in[6];  // (32,3)
    float* out = (float*)d_out;

    char* ws = (char*)d_ws;
    ull* parts2 = (ull*)ws;                      // 1536*640*8 = 7,864,320 B
    ws += (size_t)B_ * PPB * SLAB * sizeof(ull);
    unsigned* cnts = (unsigned*)ws;              // 1536*4 B (fully rewritten)

    topk_part_kernel<<<B_ * C_ * PARTS, BLK, 0, stream>>>(heat, parts2, cnts);
    merge_geom_kernel<<<B_, BLK, 0, stream>>>(
        parts2, cnts, reg, trans, Kmat, sz, hcam, dimen, out);
}

// Round 10
// 222.415 us; speedup vs baseline: 1.0223x; 1.0223x over previous
//
#include <hip/hip_runtime.h>
#include <math.h>

#define B_ 32
#define C_ 3
#define H_ 256
#define W_ 832
#define HW_ (H_*W_)
#define NQ (W_/4)               // 208 quads (float4 columns) per row
#define K_ 100
#define RPB 16                  // rows per block
#define PARTS (H_/RPB)          // 16 parts per channel
#define BLK 256
#define CAP 2048                // per-part LDS candidate cap (expected ~1480)
#define NB 2048                 // radix digit bins (11 bits)
#define TIE_CAP 128
#define SEL_PASSES 6
#define QPW 62                  // emitting quads per wave (overlapped mapping)
#define SA 128                  // tier-A slots/part (expected ~7 keys)
#define SB 512                  // tier-B slots/part (expected ~215 keys)
#define T_A 0.9995f             // tier-A threshold: ~320 keys/batch >= T_A
#define T_B 0.982f              // tier-B floor (insurance tier)
#define PPB (C_*PARTS)          // 48 parts per batch
#define SLAB (SA+SB)

typedef unsigned long long ull;

// Descending bitonic sort of N (power of two) 64-bit keys in LDS (small N only).
template<int N>
__device__ inline void bitonic_sort_desc(ull* s) {
    for (int k = 2; k <= N; k <<= 1) {
        for (int j = k >> 1; j > 0; j >>= 1) {
            __syncthreads();
            for (int i = threadIdx.x; i < N; i += BLK) {
                int ixj = i ^ j;
                if (ixj > i) {
                    ull a = s[i], b = s[ixj];
                    bool up = ((i & k) == 0);
                    if (up ? (a < b) : (a > b)) { s[i] = b; s[ixj] = a; }
                }
            }
        }
    }
    __syncthreads();
}

// Given hist[NB] (digit counts, group total >= kneed), find digit d where the
// suffix count crosses kneed. Shuffle-based suffix scan, 2 barriers.
__device__ inline void find_digit(const unsigned* __restrict__ hist,
                                  unsigned* __restrict__ wtot,
                                  const int kneed,
                                  int* __restrict__ d_s,
                                  int* __restrict__ krem_s,
                                  int* __restrict__ m_s) {
    const int tid = threadIdx.x;
    const int lane = tid & 63;
    const int wid = tid >> 6;
    unsigned l[8];
    unsigned Ls = 0;
    #pragma unroll
    for (int j = 0; j < 8; ++j) { l[j] = hist[tid * 8 + j]; Ls += l[j]; }
    unsigned x = Ls;
    #pragma unroll
    for (int off = 1; off < 64; off <<= 1) {
        unsigned y = __shfl_down(x, off);
        if (lane + off < 64) x += y;
    }
    if (lane == 0) wtot[wid] = x;   // wave totals
    __syncthreads();
    unsigned tail = 0;
    #pragma unroll
    for (int w = 0; w < 4; ++w) if (w > wid) tail += wtot[w];
    unsigned s = x - Ls + tail;     // count of keys strictly above this range
    #pragma unroll
    for (int j = 7; j >= 0; --j) {
        const unsigned Sj = s + l[j];
        if (Sj >= (unsigned)kneed && s < (unsigned)kneed) {  // unique thread
            *d_s = tid * 8 + j;
            *krem_s = kneed - (int)s;
            *m_s = (int)l[j];
        }
        s = Sj;
    }
    __syncthreads();
}

// ---------------------------------------------------------------------------
// Exact top-K_ select from LDS buf[0..cnt) (cnt >= K_) into dst[0..K_)
// (unsorted; dst may be global or LDS). MSB-first 2048-way radix with early
// exit to an exact O(m^2) tie rank once the threshold group fits TIE_CAP.
// Pass 0 wave-aggregated (concentrated top-bit digits), later passes direct.
// sh: int[5] {ocnt, tcnt, d, krem, m}.
// ---------------------------------------------------------------------------
__device__ inline void select_topk(const ull* __restrict__ buf, const int cnt,
                                   ull* __restrict__ dst,
                                   unsigned* __restrict__ hist,
                                   ull* __restrict__ tie,
                                   unsigned* __restrict__ wtot,
                                   int* __restrict__ sh) {
    const int tid = threadIdx.x;
    const int lane = tid & 63;
    if (tid == 0) sh[0] = 0;                 // ocnt
    int kneed = K_;
    int pshift = 0;                          // valid for pass > 0
    ull prefix = 0;
    for (int pass = 0; pass < SEL_PASSES; ++pass) {
        const int rs = 53 - 11 * pass;
        const int shift = (rs > 0) ? rs : 0;
        #pragma unroll
        for (int j = 0; j < NB / BLK; ++j) hist[tid + j * BLK] = 0u;
        if (tid == 0) sh[1] = 0;             // tcnt
        __syncthreads();
        if (pass == 0) {
            for (int i = tid; i < cnt; i += BLK) {
                const unsigned dg = (unsigned)(buf[i] >> shift) & 2047u;
                ull unclaimed = __ballot(1);
                while (unclaimed) {
                    const int leader = __ffsll((long long)unclaimed) - 1;
                    const unsigned ldg = __shfl(dg, leader);
                    const ull same = __ballot(dg == ldg);
                    if (lane == leader)
                        atomicAdd(&hist[ldg], (unsigned)__popcll(same));
                    unclaimed &= ~same;
                }
            }
        } else {
            for (int i = tid; i < cnt; i += BLK) {
                const ull key = buf[i];
                if ((key >> pshift) != prefix) continue;
                atomicAdd(&hist[(unsigned)(key >> shift) & 2047u], 1u);
            }
        }
        __syncthreads();
        find_digit(hist, wtot, kneed, &sh[2], &sh[3], &sh[4]);
        const int d = sh[2], krem = sh[3], m = sh[4];
        const bool last = (m <= TIE_CAP) || (pass == SEL_PASSES - 1);
        for (int i = tid; i < cnt; i += BLK) {
            const ull key = buf[i];
            if (pass > 0 && (key >> pshift) != prefix) continue;
            const int dg = (int)((unsigned)(key >> shift) & 2047u);
            if (dg > d) {
                dst[atomicAdd(&sh[0], 1)] = key;
            } else if (last && dg == d) {
                const int p = atomicAdd(&sh[1], 1);
                if (p < TIE_CAP) tie[p] = key;
            }
        }
        __syncthreads();
        if (last) {
            const int n1 = K_ - krem;
            if (sh[1] <= TIE_CAP) {
                const int mm = sh[1];
                for (int i = tid; i < mm; i += BLK) {
                    const ull key = tie[i];
                    int r = 0;
                    for (int j = 0; j < mm; ++j) r += (tie[j] > key) ? 1 : 0;
                    if (r < krem) dst[n1 + r] = key;
                }
            } else {
                for (int i = tid; i < krem; i += BLK) dst[n1 + i] = tie[0];
            }
            __syncthreads();
            return;
        }
        prefix = (prefix << 11) | (ull)(unsigned)d;
        pshift = shift;
        kneed = krem;
    }
}

// Same select over a global array (slow-path padded slab scan).
__device__ inline void select_topk_g(const ull* __restrict__ A, const int cnt,
                                     ull* __restrict__ dst,
                                     unsigned* __restrict__ hist,
                                     ull* __restrict__ tie,
                                     unsigned* __restrict__ wtot,
                                     int* __restrict__ sh) {
    const int tid = threadIdx.x;
    const int lane = tid & 63;
    if (tid == 0) sh[0] = 0;
    int kneed = K_;
    int pshift = 0;
    ull prefix = 0;
    for (int pass = 0; pass < SEL_PASSES; ++pass) {
        const int rs = 53 - 11 * pass;
        const int shift = (rs > 0) ? rs : 0;
        #pragma unroll
        for (int j = 0; j < NB / BLK; ++j) hist[tid + j * BLK] = 0u;
        if (tid == 0) sh[1] = 0;
        __syncthreads();
        if (pass == 0) {
            for (int i = tid; i < cnt; i += BLK) {
                const unsigned dg = (unsigned)(A[i] >> shift) & 2047u;
                ull unclaimed = __ballot(1);
                while (unclaimed) {
                    const int leader = __ffsll((long long)unclaimed) - 1;
                    const unsigned ldg = __shfl(dg, leader);
                    const ull same = __ballot(dg == ldg);
                    if (lane == leader)
                        atomicAdd(&hist[ldg], (unsigned)__popcll(same));
                    unclaimed &= ~same;
                }
            }
        } else {
            for (int i = tid; i < cnt; i += BLK) {
                const ull key = A[i];
                if ((key >> pshift) != prefix) continue;
                atomicAdd(&hist[(unsigned)(key >> shift) & 2047u], 1u);
            }
        }
        __syncthreads();
        find_digit(hist, wtot, kneed, &sh[2], &sh[3], &sh[4]);
        const int d = sh[2], krem = sh[3], m = sh[4];
        const bool last = (m <= TIE_CAP) || (pass == SEL_PASSES - 1);
        for (int i = tid; i < cnt; i += BLK) {
            const ull key = A[i];
            if (pass > 0 && (key >> pshift) != prefix) continue;
            const int dg = (int)((unsigned)(key >> shift) & 2047u);
            if (dg > d) {
                dst[atomicAdd(&sh[0], 1)] = key;
            } else if (last && dg == d) {
                const int p = atomicAdd(&sh[1], 1);
                if (p < TIE_CAP) tie[p] = key;
            }
        }
        __syncthreads();
        if (last) {
            const int n1 = K_ - krem;
            if (sh[1] <= TIE_CAP) {
                const int mm = sh[1];
                for (int i = tid; i < mm; i += BLK) {
                    const ull key = tie[i];
                    int r = 0;
                    for (int j = 0; j < mm; ++j) r += (tie[j] > key) ? 1 : 0;
                    if (r < krem) dst[n1 + r] = key;
                }
            } else {
                for (int i = tid; i < krem; i += BLK) dst[n1 + i] = tie[0];
            }
            __syncthreads();
            return;
        }
        prefix = (prefix << 11) | (ull)(unsigned)d;
        pshift = shift;
        kneed = krem;
    }
}

// ---------------------------------------------------------------------------
// Kernel 1: separable 3x3 peak detect (row loop identical to R4). Epilogue:
// two-tier threshold classification, NO select on the common path:
//   tier A: v >= T_A (~7/part) -> first SA slots;  tier B: [T_B,T_A) (~215)
//   -> next SB slots; both compacted, tails zero-padded (pads read only by
//   the never-taken slow path). Per-part fallback (cap overflow, or survivors
//   < min(cc,K_)): exact top-100 select into A — a part's top-100 always
//   covers its possible contribution to the batch top-100, so correctness is
//   airtight regardless of thresholds. Counts packed into cnts[part]:
//   cntA | gA<<8 | cntB<<16, where gA = #A-region keys >= T_A (capped).
// ---------------------------------------------------------------------------
__global__ void __launch_bounds__(BLK) topk_part_kernel(
        const float* __restrict__ heat, ull* __restrict__ parts2,
        unsigned* __restrict__ cnts) {
    const int chan = blockIdx.x / PARTS;   // b*C + c
    const int c    = chan % C_;
    const int part = blockIdx.x % PARTS;
    const float* __restrict__ hp = heat + (size_t)chan * HW_;
    const int r0 = part * RPB;
    const int tid = threadIdx.x;
    const int lane = tid & 63;
    const int wid = tid >> 6;

    const int q = QPW * wid + lane - 1;          // quad this lane carries
    const bool ghost = (q < 0) || (q >= NQ);     // outside image -> -inf colmax
    const int qc = (q < 0) ? 0 : ((q >= NQ) ? NQ - 1 : q);
    const bool emitter = (lane >= 1) && (lane <= QPW) && !ghost;

    __shared__ ull sbuf[CAP];
    __shared__ unsigned hist[NB];
    __shared__ ull tie[TIE_CAP];
    __shared__ unsigned wtot[4];
    __shared__ int scnt, nA, nB, wpA, wpB;
    __shared__ int selsh[5];
    if (tid == 0) { scnt = 0; nA = 0; nB = 0; wpA = 0; wpB = 0; }

    float4 R[6];
    #pragma unroll
    for (int j = 0; j < 6; ++j) {
        int row = r0 - 1 + j;
        row = (row < 0) ? 0 : ((row > H_ - 1) ? H_ - 1 : row);
        R[j] = reinterpret_cast<const float4*>(hp + (size_t)row * W_)[qc];
    }
    __syncthreads();   // counters=0 visible before any append

    #pragma unroll
    for (int r = 0; r < RPB; ++r) {
        const int y = r0 + r;
        const float4 ra = R[r % 6];
        const float4 rb = R[(r + 1) % 6];
        const float4 rc = R[(r + 2) % 6];
        if (r < RPB - 4) {
            const int yn = (y + 5 > H_ - 1) ? H_ - 1 : y + 5;
            R[r % 6] = reinterpret_cast<const float4*>(hp + (size_t)yn * W_)[qc];
        }

        float4 vm;
        vm.x = fmaxf(fmaxf(ra.x, rb.x), rc.x);
        vm.y = fmaxf(fmaxf(ra.y, rb.y), rc.y);
        vm.z = fmaxf(fmaxf(ra.z, rb.z), rc.z);
        vm.w = fmaxf(fmaxf(ra.w, rb.w), rc.w);
        if (ghost) { vm.x = vm.y = vm.z = vm.w = -INFINITY; }

        const float left  = __shfl_up(vm.w, 1);
        const float right = __shfl_down(vm.x, 1);

        const float vn[6] = {left, vm.x, vm.y, vm.z, vm.w, right};
        const float vv[4] = {rb.x, rb.y, rb.z, rb.w};
        ull m[4];
        bool pk[4];
        #pragma unroll
        for (int i = 0; i < 4; ++i) {
            pk[i] = emitter && (vv[i] >= vn[i]) && (vv[i] >= vn[i+1]) && (vv[i] >= vn[i+2]);
            m[i] = __ballot(pk[i]);
        }
        const int tot = (int)(__popcll(m[0]) + __popcll(m[1]) +
                              __popcll(m[2]) + __popcll(m[3]));
        if (tot) {           // wave-uniform
            int base = 0;
            if (lane == 0) base = atomicAdd(&scnt, tot);
            base = __shfl(base, 0);
            int off = 0;
            #pragma unroll
            for (int i = 0; i < 4; ++i) {
                if (pk[i]) {
                    const unsigned p = (unsigned)(y * W_ + q * 4 + i);
                    const unsigned tiek = ((unsigned)c << 18) | p;
                    const ull key = ((ull)__float_as_uint(vv[i]) << 32) | (ull)(~tiek);
                    const int rank = (int)__popcll(m[i] & ((1ULL << lane) - 1ULL));
                    const int pos = base + off + rank;
                    if (pos < CAP) sbuf[pos] = key;
                }
                off += (int)__popcll(m[i]);
            }
        }
    }
    __syncthreads();   // scnt + sbuf final

    const int cc = (scnt < CAP) ? scnt : CAP;
    ull* oA = parts2 + (size_t)blockIdx.x * SLAB;
    ull* oB = oA + SA;

    // classify-count (wave-aggregated LDS atomics)
    for (int i0 = wid * 64; i0 < cc; i0 += BLK) {
        const int i = i0 + lane;
        float v = -1.f;
        if (i < cc) v = __uint_as_float((unsigned)(sbuf[i] >> 32));
        const ull ma = __ballot(v >= T_A);
        const ull mb = __ballot(v >= T_B && v < T_A);
        if (lane == 0) {
            if (ma) atomicAdd(&nA, (int)__popcll(ma));
            if (mb) atomicAdd(&nB, (int)__popcll(mb));
        }
    }
    __syncthreads();
    const int nhA = nA, nhB = nB;
    const bool fb = (nhA > SA) || (nhB > SB) ||
                    ((nhA + nhB) < K_ && (nhA + nhB) < cc);

    int cntA, gA, cntB;
    if (cc <= K_) {
        // few candidates: emit everything into A (complete, nothing dropped)
        for (int i = tid; i < cc; i += BLK) oA[i] = sbuf[i];
        for (int i = cc + tid; i < SA; i += BLK) oA[i] = 0ULL;
        for (int i = tid; i < SB; i += BLK) oB[i] = 0ULL;
        cntA = cc; gA = (nhA < cc) ? nhA : cc; cntB = 0;
    } else if (!fb) {
        // common path: compact A and B tiers (no select)
        for (int i0 = wid * 64; i0 < cc; i0 += BLK) {
            const int i = i0 + lane;
            ull key = 0ULL; float v = -1.f;
            if (i < cc) { key = sbuf[i]; v = __uint_as_float((unsigned)(key >> 32)); }
            const bool fa  = (v >= T_A);
            const bool fbb = (v >= T_B) && (v < T_A);
            const ull ma = __ballot(fa);
            const ull mb = __ballot(fbb);
            int ba = 0, bb = 0;
            if (lane == 0) {
                if (ma) ba = atomicAdd(&wpA, (int)__popcll(ma));
                if (mb) bb = atomicAdd(&wpB, (int)__popcll(mb));
            }
            ba = __shfl(ba, 0); bb = __shfl(bb, 0);
            if (fa)  oA[ba + (int)__popcll(ma & ((1ULL << lane) - 1ULL))] = key;
            if (fbb) oB[bb + (int)__popcll(mb & ((1ULL << lane) - 1ULL))] = key;
        }
        for (int i = nhA + tid; i < SA; i += BLK) oA[i] = 0ULL;
        for (int i = nhB + tid; i < SB; i += BLK) oB[i] = 0ULL;
        cntA = nhA; gA = nhA; cntB = nhB;
    } else {
        // airtight fallback: exact part top-100 into A
        select_topk(sbuf, cc, oA, hist, tie, wtot, selsh);
        for (int i = K_ + tid; i < SA; i += BLK) oA[i] = 0ULL;
        for (int i = tid; i < SB; i += BLK) oB[i] = 0ULL;
        cntA = K_; gA = (nhA < K_) ? nhA : K_; cntB = 0;
    }
    if (tid == 0)
        cnts[blockIdx.x] = (unsigned)cntA | ((unsigned)gA << 8) |
                           ((unsigned)cntB << 16);
}

// ---------------------------------------------------------------------------
// Kernel 2 (fused merge+geom): per-batch exact top-100.
// Fast path (Sum gA >= 100 and Sum cntA <= CAP — always in practice): gather
// the ~320 tier-A keys into LDS and select there. Proof: Sum gA >= 100 =>
// >=100 batch keys >= T_A => batch-100th >= T_A => every top-100 key is in
// its part's A region (normal parts store ALL keys >= T_A; fallback parts
// store their top-100 which bounds their contribution). Slow path: padded
// A||B slab scan (R7 semantics). Then sort-128 + geometry from LDS.
// ---------------------------------------------------------------------------
__global__ void __launch_bounds__(BLK) merge_geom_kernel(
        const ull* __restrict__ parts2, const unsigned* __restrict__ cnts,
        const float* __restrict__ reg,
        const float* __restrict__ trans, const float* __restrict__ Km,
        const float* __restrict__ sz, const float* __restrict__ hcam,
        const float* __restrict__ dimen, float* __restrict__ out) {
    const int b = blockIdx.x;
    const int tid = threadIdx.x;
    __shared__ ull buf[CAP];
    __shared__ unsigned hist[NB];
    __shared__ ull sel[128];
    __shared__ ull tie[TIE_CAP];
    __shared__ unsigned wtot[4];
    __shared__ int selsh[5];
    __shared__ int cA[PPB], gAsh[PPB], offA[PPB + 1];
    __shared__ int gsum_s;

    const int p0 = b * PPB;
    if (tid < PPB) {
        const unsigned w = cnts[p0 + tid];
        cA[tid]  = (int)(w & 255u);
        gAsh[tid] = (int)((w >> 8) & 255u);
    }
    if (tid < 128) sel[tid] = 0ULL;
    __syncthreads();
    if (tid == 0) {
        int acc = 0, g = 0;
        for (int j = 0; j < PPB; ++j) { offA[j] = acc; acc += cA[j]; g += gAsh[j]; }
        offA[PPB] = acc; gsum_s = g;
    }
    __syncthreads();
    const int ntot = offA[PPB];
    const int gsum = gsum_s;

    if (gsum >= K_ && ntot <= CAP) {
        // flattened gather of counted A prefixes
        for (int t = tid; t < ntot; t += BLK) {
            int j = 0;
            while (offA[j + 1] <= t) ++j;
            buf[t] = parts2[(size_t)(p0 + j) * SLAB + (t - offA[j])];
        }
        __syncthreads();
        if (ntot <= K_) {
            for (int i = tid; i < ntot; i += BLK) sel[i] = buf[i];
            __syncthreads();
        } else {
            select_topk(buf, ntot, sel, hist, tie, wtot, selsh);
        }
    } else {
        // airtight slow path: scan the full zero-padded A||B slab
        select_topk_g(parts2 + (size_t)p0 * SLAB, PPB * SLAB,
                      sel, hist, tie, wtot, selsh);
    }

    bitonic_sort_desc<128>(sel);   // has leading __syncthreads

    // ---- geometry, one thread per detection ----
    for (int i = tid; i < K_; i += BLK) {
        const ull key = sel[i];
        const unsigned tiek = ~(unsigned)(key & 0xFFFFFFFFULL);
        const float score = __uint_as_float((unsigned)(key >> 32));
        const float clsf = (float)((tiek >> 18) & 3u);
        unsigned hw = tiek & 0x3FFFFu;
        if (hw >= HW_) hw = 0;   // pad entries: score==0, row zeroed below
        const float xs = (float)(hw % W_);
        const float ys = (float)(hw / W_);

        const float* rg = reg + (size_t)b * 4 * HW_;
        const float delta = rg[hw];
        const float off_u = rg[HW_ + hw];
        const float ori0  = rg[2 * HW_ + hw];
        const float ori1  = rg[3 * HW_ + hw];

        const float* T = trans + b * 9;
        const float t00=T[0], t01=T[1], t02=T[2], t10=T[3], t11=T[4], t12=T[5],
                    t20=T[6], t21=T[7], t22=T[8];
        const float det3 = t00*(t11*t22 - t12*t21) - t01*(t10*t22 - t12*t20)
                         + t02*(t10*t21 - t11*t20);
        const float idt = 1.0f / det3;
        const float i00 = (t11*t22 - t12*t21)*idt;
        const float i01 = (t02*t21 - t01*t22)*idt;
        const float i02 = (t01*t12 - t02*t11)*idt;

        const float pu = xs + off_u;
        const float img_x = i00*pu + i01*ys + i02;

        const float* Kb = Km + b * 9;
        const float k00=Kb[0],k01=Kb[1],k02=Kb[2],k10=Kb[3],k11=Kb[4],k12=Kb[5],
                    k20=Kb[6],k21=Kb[7],k22=Kb[8];
        const float fx = k00, fy = k11, cx = k02;
        const float h = hcam[b];
        float d0 = dimen[b*3+0], d1 = dimen[b*3+1], d2 = dimen[b*3+2];
        if (!isfinite(d0)) d0 = 3.88f;
        if (!isfinite(d1)) d1 = 1.63f;
        if (!isfinite(d2)) d2 = 1.53f;

        const float h_ref = h - d1 * 0.5f;
        const float fyh = fy * fabsf(h_ref);
        const float log_dv_ref = logf(fmaxf(fyh, 1e-7f) / 28.01f);
        const float log_dv = fminf(fmaxf(log_dv_ref + delta, -4.0f), 8.0f);
        const float depth = fminf(fmaxf(fyh * expf(-log_dv), 0.5f), 120.0f);
        const float px = (img_x - cx) * depth / fx;

        const float PI_F  = 3.14159265358979323846f;
        const float ray = atanf(px / (depth + 1e-7f));
        float alpha = atanf(ori0 / (ori1 + 1e-7f));
        alpha += (ori1 >= 0.0f) ? -1.5707963267948966f : 1.5707963267948966f;
        float roty = alpha + ray;
        if (roty >  PI_F) roty -= 6.283185307179586f;
        if (roty < -PI_F) roty += 6.283185307179586f;

        const float cosr = cosf(roty), sinr = sinf(roty);
        const float cx8[8] = {-0.5f, 0.5f, 0.5f, 0.5f, 0.5f,-0.5f,-0.5f,-0.5f};
        const float cy8[8] = {-1.0f,-1.0f, 0.0f, 0.0f,-1.0f,-1.0f, 0.0f, 0.0f};
        const float cz8[8] = {-0.5f,-0.5f,-0.5f, 0.5f, 0.5f, 0.5f, 0.5f,-0.5f};
        float umin = 1e30f, umax = -1e30f, vmin = 1e30f, vmax = -1e30f;
        #pragma unroll
        for (int j = 0; j < 8; ++j) {
            const float xc = d0 * cx8[j];
            const float yc = d1 * cy8[j];
            const float zc = d2 * cz8[j];
            const float X = cosr*xc + sinr*zc + px;
            const float Y = yc + h;
            const float Z = -sinr*xc + cosr*zc + depth;
            const float w = k20*X + k21*Y + k22*Z;
            const float u = (k00*X + k01*Y + k02*Z) / w;
            const float v = (k10*X + k11*Y + k12*Z) / w;
            umin = fminf(umin, u); umax = fmaxf(umax, u);
            vmin = fminf(vmin, v); vmax = fmaxf(vmax, v);
        }
        const float img_w = sz[0], img_h = sz[1];
        const float xmin = fminf(fmaxf(umin, 0.0f), img_w);
        const float xmax = fminf(fmaxf(umax, 0.0f), img_w);
        const float ymin = fminf(fmaxf(vmin, 0.0f), img_h);
        const float ymax = fminf(fmaxf(vmax, 0.0f), img_h);

        const float keep = (score > 0.25f) ? 1.0f : 0.0f;
        float* o = out + (size_t)(b * K_ + i) * 14;
        o[0]  = clsf  * keep;
        o[1]  = alpha * keep;
        o[2]  = xmin  * keep;
        o[3]  = ymin  * keep;
        o[4]  = xmax  * keep;
        o[5]  = ymax  * keep;
        o[6]  = d1    * keep;   // pred_dims = roll(dims,-1)
        o[7]  = d2    * keep;
        o[8]  = d0    * keep;
        o[9]  = px    * keep;
        o[10] = h     * keep;
        o[11] = depth * keep;
        o[12] = roty  * keep;
        o[13] = score * keep;
    }
}

extern "C" void kernel_launch(void* const* d_in, const int* in_sizes, int n_in,
                              void* d_out, int out_size, void* d_ws, size_t ws_size,
                              hipStream_t stream) {
    const float* heat  = (const float*)d_in[0];  // (32,3,256,832)
    const float* reg   = (const float*)d_in[1];  // (32,4,256,832)
    const float* trans = (const float*)d_in[2];  // (32,3,3)
    const float* Kmat  = (const float*)d_in[3];  // (32,3,3)
    const float* sz    = (const float*)d_in[4];  // (32,2)
    const float* hcam  = (const float*)d_in[5];  // (32,)
    const float* dimen = (const float*)d_in[6];  // (32,3)
    float* out = (float*)d_out;

    char* ws = (char*)d_ws;
    ull* parts2 = (ull*)ws;                      // 1536*640*8 = 7,864,320 B
    ws += (size_t)B_ * PPB * SLAB * sizeof(ull);
    unsigned* cnts = (unsigned*)ws;              // 1536*4 B (fully rewritten)

    topk_part_kernel<<<B_ * C_ * PARTS, BLK, 0, stream>>>(heat, parts2, cnts);
    merge_geom_kernel<<<B_, BLK, 0, stream>>>(
        parts2, cnts, reg, trans, Kmat, sz, hcam, dimen, out);
}